// Round 1
// baseline (97.264 us; speedup 1.0000x reference)
//
#include <hip/hip_runtime.h>
#include <math.h>

#define D_FEAT 64
#define N_ETYPES 8
#define EPS_F 1e-8f

typedef float v4f __attribute__((ext_vector_type(4)));

// ---------------------------------------------------------------------------
// Kernel 1: per-node pass. 16 lanes per node, float4 per lane (64 floats/row).
//   - out row   = feat row (bit-exact copy; also the zero-init of the rare
//                 path's accumulation target, since a zero row copies zeros)
//   - side[n]   = { nw_exp = mask*exp(feat.attn), 0 (sum init), mask, 0 }
//   - flag = 1 iff some all-zero feature row exists
// flag/counter are zeroed by an 8-byte hipMemsetAsync enqueued BEFORE this
// kernel (stream-ordered -> race-free, poison-proof gate). Previously the
// gate relied on workspace poison != 1; now it is exact.
// ---------------------------------------------------------------------------
__global__ void node_kernel(const float* __restrict__ feat,
                            const float* __restrict__ attn,
                            float* __restrict__ out,
                            v4f* __restrict__ side,
                            int* __restrict__ flag,
                            int N) {
    int gid  = blockIdx.x * blockDim.x + threadIdx.x;
    int node = gid >> 4;          // 16 lanes per node row
    int sub  = gid & 15;          // this lane's float4 within the row
    if (node >= N) return;

    const v4f f = __builtin_nontemporal_load(((const v4f*)feat) + (size_t)node * 16 + sub);
    const v4f a = ((const v4f*)attn)[sub];   // cached, reused by every block

    // out = feat (bit-exact; final value for nonzero rows, zero-init otherwise)
    __builtin_nontemporal_store(f, ((v4f*)out) + (size_t)node * 16 + sub);

    float abss = fabsf(f.x) + fabsf(f.y) + fabsf(f.z) + fabsf(f.w);
    float dot  = f.x * a.x + f.y * a.y + f.z * a.z + f.w * a.w;

    // reduce across the 16-lane group (xor offsets < 16 stay inside the group)
    #pragma unroll
    for (int off = 1; off < 16; off <<= 1) {
        abss += __shfl_xor(abss, off);
        dot  += __shfl_xor(dot,  off);
    }

    if (sub == 0) {
        float m = (abss == 0.0f) ? 0.0f : 1.0f;
        v4f s;
        s.x = (m != 0.0f) ? expf(dot) : 0.0f;  // nw_exp (TEMPERATURE == 1)
        s.y = 0.0f;                             // nw_exp_sum accumulator init
        s.z = m;                                // mask
        s.w = 0.0f;
        side[node] = s;    // lanes 0/16/32/48 of a wave -> contiguous 64 B
        if (m == 0.0f) *flag = 1;
    }
}

// ---------------------------------------------------------------------------
// Kernel 2: gated finish — edge aggregation + denom fixup in one launch.
// Steady state (*flag == 0): every block exits after one cached word load.
// Rare path (some zero row exists):
//   phase 1: grid-stride over edges; for unmasked dst, accumulate
//            nw_exp[src] into side[dst].y and nw_exp[src]*ew*feat[src]
//            into out[dst] (pre-zeroed by the feat copy).
//   phase 2: block-completion barrier via counter; the LAST block divides
//            every unmasked row by denom. Slow (one block) but correct, and
//            only ever taken when an all-zero feature row exists.
// ---------------------------------------------------------------------------
__global__ void finish_kernel(const int* __restrict__ src,
                              const int* __restrict__ dst,
                              const int* __restrict__ e_feat,
                              const float* __restrict__ feat,
                              v4f* __restrict__ side,
                              const float* __restrict__ edge_weight,
                              const float* __restrict__ edge_weight_param,
                              const int* __restrict__ flag,
                              int* __restrict__ counter,
                              float* __restrict__ out,
                              int E, int N) {
    if (*flag != 1) return;   // steady state: exit immediately (flag memset 0)

    // ---- phase 1: edge accumulation (grid-stride) ----
    int stride = gridDim.x * blockDim.x;
    for (int e = blockIdx.x * blockDim.x + threadIdx.x; e < E; e += stride) {
        int d = dst[e];
        if (side[d].z != 0.0f) continue;  // dst keeps its original features
        int s = src[e];
        float w = side[s].x;              // nw_exp (0 for zero-mask sources)
        atomicAdd(&((float*)&side[d])[1], w);   // nw_exp_sum
        int t = e_feat[e] - 1;
        float ewv = 1.0f;
        #pragma unroll
        for (int j = 0; j < N_ETYPES; ++j)
            ewv += edge_weight[t * N_ETYPES + j] * edge_weight_param[j];
        float scale = w * ewv;
        const float* fs = feat + (size_t)s * D_FEAT;
        float*       od = out  + (size_t)d * D_FEAT;
        #pragma unroll 4
        for (int k = 0; k < D_FEAT; ++k)
            atomicAdd(&od[k], fs[k] * scale);
    }

    // ---- phase 2: completion barrier; last block does the fixup ----
    __threadfence();              // order this block's atomics before signal
    __syncthreads();
    __shared__ int is_last;
    if (threadIdx.x == 0) {
        int old = atomicAdd(counter, 1);
        is_last = (old == (int)gridDim.x - 1) ? 1 : 0;
    }
    __syncthreads();
    if (!is_last) return;
    __threadfence();              // acquire other blocks' accumulations

    for (int n = threadIdx.x; n < N; n += blockDim.x) {
        v4f s = side[n];
        if (s.z != 0.0f) continue;
        float denom = (s.y < EPS_F) ? 1.0f : s.y;
        float* row = out + (size_t)n * D_FEAT;
        #pragma unroll 4
        for (int k = 0; k < D_FEAT; ++k)
            row[k] = row[k] / denom;   // keep exact reference order (ft/denom)
    }
}

extern "C" void kernel_launch(void* const* d_in, const int* in_sizes, int n_in,
                              void* d_out, int out_size, void* d_ws, size_t ws_size,
                              hipStream_t stream) {
    const float* feat              = (const float*)d_in[0];
    const float* attn              = (const float*)d_in[1];
    const float* edge_weight       = (const float*)d_in[2];
    const float* edge_weight_param = (const float*)d_in[3];
    const int*   src               = (const int*)d_in[4];
    const int*   dst               = (const int*)d_in[5];
    const int*   e_feat            = (const int*)d_in[6];
    float*       out               = (float*)d_out;

    const int N = in_sizes[0] / D_FEAT;
    const int E = in_sizes[4];

    // workspace layout (~1.6 MB): side[N] (float4) | flag | counter
    v4f* side    = (v4f*)d_ws;
    int* flag    = (int*)(side + N);
    int* counter = flag + 1;

    // Exact, race-free gate init: zero {flag, counter} before node_kernel.
    // (stream-ordered + graph-capturable; removes reliance on poison != 1)
    hipMemsetAsync(flag, 0, 2 * sizeof(int), stream);

    const int threadsA = 256;
    const int nodesPerBlock = threadsA / 16;   // 16 lanes per node
    node_kernel<<<(N + nodesPerBlock - 1) / nodesPerBlock, threadsA, 0, stream>>>(
        feat, attn, out, side, flag, N);

    // Gated finish: small grid -> steady-state cost is just dispatch + one
    // cached word per block; rare path covers all E via grid-stride.
    finish_kernel<<<256, 256, 0, stream>>>(
        src, dst, e_feat, feat, side, edge_weight, edge_weight_param,
        flag, counter, out, E, N);
}

// Round 2
// 94.564 us; speedup vs baseline: 1.0286x; 1.0286x over previous
//
#include <hip/hip_runtime.h>
#include <math.h>

#define D_FEAT 64
#define N_ETYPES 8
#define EPS_F 1e-8f

typedef float v4f __attribute__((ext_vector_type(4)));

// ---------------------------------------------------------------------------
// Kernel 1: per-node pass. 16 lanes per node, float4 per lane (64 floats/row).
//   - out row   = feat row (bit-exact copy; also the zero-init of the rare
//                 path's accumulation target, since a zero row copies zeros)
//   - side[n]   = { nw_exp = mask*exp(feat.attn), 0 (sum init), mask, 0 }
//   - flag = 1 iff some all-zero feature row exists
//   - counter = 0 (rare-path completion barrier; stream order guarantees this
//                  is visible before the finish kernel runs)
// Gating note: finish kernel runs its full path iff *flag == 1; node only
// ever writes 1. Any pre-existing (poisoned) flag value is safe:
//   poison != 1 && zero row exists -> node writes 1 -> finish runs (correct)
//   poison == 1 && no zero row     -> finish runs, per-element checks no-op
// (Round-1 probe measured the explicit memset gate-init at +3 us for zero
//  behavioral difference; reverted to the in-kernel init.)
// ---------------------------------------------------------------------------
__global__ void node_kernel(const float* __restrict__ feat,
                            const float* __restrict__ attn,
                            float* __restrict__ out,
                            v4f* __restrict__ side,
                            int* __restrict__ flag,
                            int* __restrict__ counter,
                            int N) {
    int gid  = blockIdx.x * blockDim.x + threadIdx.x;
    int node = gid >> 4;          // 16 lanes per node row
    int sub  = gid & 15;          // this lane's float4 within the row
    if (gid == 0) *counter = 0;   // init rare-path barrier (ws is poisoned)
    if (node >= N) return;

    const v4f f = __builtin_nontemporal_load(((const v4f*)feat) + (size_t)node * 16 + sub);
    const v4f a = ((const v4f*)attn)[sub];   // cached, reused by every block

    // out = feat (bit-exact; final value for nonzero rows, zero-init otherwise)
    __builtin_nontemporal_store(f, ((v4f*)out) + (size_t)node * 16 + sub);

    float abss = fabsf(f.x) + fabsf(f.y) + fabsf(f.z) + fabsf(f.w);
    float dot  = f.x * a.x + f.y * a.y + f.z * a.z + f.w * a.w;

    // reduce across the 16-lane group (xor offsets < 16 stay inside the group)
    #pragma unroll
    for (int off = 1; off < 16; off <<= 1) {
        abss += __shfl_xor(abss, off);
        dot  += __shfl_xor(dot,  off);
    }

    if (sub == 0) {
        float m = (abss == 0.0f) ? 0.0f : 1.0f;
        v4f s;
        s.x = (m != 0.0f) ? expf(dot) : 0.0f;  // nw_exp (TEMPERATURE == 1)
        s.y = 0.0f;                             // nw_exp_sum accumulator init
        s.z = m;                                // mask
        s.w = 0.0f;
        side[node] = s;    // lanes 0/16/32/48 of a wave -> contiguous 64 B
        if (m == 0.0f) *flag = 1;
    }
}

// ---------------------------------------------------------------------------
// Kernel 2: gated finish — edge aggregation + denom fixup in one launch.
// Steady state (*flag != 1): every block exits after one L2-hit word load.
// Rare path (some zero row exists):
//   phase 1: grid-stride over edges; for unmasked dst, accumulate
//            nw_exp[src] into side[dst].y and nw_exp[src]*ew*feat[src]
//            into out[dst] (pre-zeroed by the feat copy).
//   phase 2: block-completion barrier via counter; the LAST block divides
//            every unmasked row by denom. Slow (one block) but correct, and
//            only ever taken when an all-zero feature row exists.
// ---------------------------------------------------------------------------
__global__ void finish_kernel(const int* __restrict__ src,
                              const int* __restrict__ dst,
                              const int* __restrict__ e_feat,
                              const float* __restrict__ feat,
                              v4f* __restrict__ side,
                              const float* __restrict__ edge_weight,
                              const float* __restrict__ edge_weight_param,
                              const int* __restrict__ flag,
                              int* __restrict__ counter,
                              float* __restrict__ out,
                              int E, int N) {
    if (*flag != 1) return;   // steady state: exit immediately

    // ---- phase 1: edge accumulation (grid-stride) ----
    int stride = gridDim.x * blockDim.x;
    for (int e = blockIdx.x * blockDim.x + threadIdx.x; e < E; e += stride) {
        int d = dst[e];
        if (side[d].z != 0.0f) continue;  // dst keeps its original features
        int s = src[e];
        float w = side[s].x;              // nw_exp (0 for zero-mask sources)
        atomicAdd(&((float*)&side[d])[1], w);   // nw_exp_sum
        int t = e_feat[e] - 1;
        float ewv = 1.0f;
        #pragma unroll
        for (int j = 0; j < N_ETYPES; ++j)
            ewv += edge_weight[t * N_ETYPES + j] * edge_weight_param[j];
        float scale = w * ewv;
        const float* fs = feat + (size_t)s * D_FEAT;
        float*       od = out  + (size_t)d * D_FEAT;
        #pragma unroll 4
        for (int k = 0; k < D_FEAT; ++k)
            atomicAdd(&od[k], fs[k] * scale);
    }

    // ---- phase 2: completion barrier; last block does the fixup ----
    __threadfence();              // order this block's atomics before signal
    __syncthreads();
    __shared__ int is_last;
    if (threadIdx.x == 0) {
        int old = atomicAdd(counter, 1);
        is_last = (old == (int)gridDim.x - 1) ? 1 : 0;
    }
    __syncthreads();
    if (!is_last) return;
    __threadfence();              // acquire other blocks' accumulations

    for (int n = threadIdx.x; n < N; n += blockDim.x) {
        v4f s = side[n];
        if (s.z != 0.0f) continue;
        float denom = (s.y < EPS_F) ? 1.0f : s.y;
        float* row = out + (size_t)n * D_FEAT;
        #pragma unroll 4
        for (int k = 0; k < D_FEAT; ++k)
            row[k] = row[k] / denom;   // keep exact reference order (ft/denom)
    }
}

extern "C" void kernel_launch(void* const* d_in, const int* in_sizes, int n_in,
                              void* d_out, int out_size, void* d_ws, size_t ws_size,
                              hipStream_t stream) {
    const float* feat              = (const float*)d_in[0];
    const float* attn              = (const float*)d_in[1];
    const float* edge_weight       = (const float*)d_in[2];
    const float* edge_weight_param = (const float*)d_in[3];
    const int*   src               = (const int*)d_in[4];
    const int*   dst               = (const int*)d_in[5];
    const int*   e_feat            = (const int*)d_in[6];
    float*       out               = (float*)d_out;

    const int N = in_sizes[0] / D_FEAT;
    const int E = in_sizes[4];

    // workspace layout (~1.6 MB): side[N] (float4) | flag | counter
    v4f* side    = (v4f*)d_ws;
    int* flag    = (int*)(side + N);
    int* counter = flag + 1;

    const int threadsA = 256;
    const int nodesPerBlock = threadsA / 16;   // 16 lanes per node
    node_kernel<<<(N + nodesPerBlock - 1) / nodesPerBlock, threadsA, 0, stream>>>(
        feat, attn, out, side, flag, counter, N);

    // Gated finish: small grid -> steady-state cost is just dispatch + one
    // cached word per block; rare path covers all E via grid-stride.
    finish_kernel<<<256, 256, 0, stream>>>(
        src, dst, e_feat, feat, side, edge_weight, edge_weight_param,
        flag, counter, out, E, N);
}